// Round 15
// baseline (53.759 us; speedup 1.0000x reference)
//
#include <hip/hip_runtime.h>
#include <hip/hip_bf16.h>

// BlockLinear: out[h*64+i][b] = sum_j W[h][i][j] * inp[h*64+j][b]
// Round 15: r14 + cross-tile software pipeline. NT=4 column-tiles per block;
// tile t+1's 32 KB global reads are issued (into a 2nd VGPR set) right after
// tile t's LDS write, so reads stay in flight through t's frag/MFMA/store
// phases. Grid 64x16 = 1024 blocks = exactly 4/CU (LDS 34 KB x4 = 136 KB).
// All r11-r14 wins kept: W frag table (L2-hot), copy-style 1 KB read instrs,
// LDS-staged C, cooperative f32x4 nt-stores on 512 B runs.
// Fragment layout (HW-validated r6-r14): lane l holds k = ks*32+8*(l>>4)+r;
// C/D: batch col m = 4*(l>>4)+reg, output row n = l&15.

constexpr int H    = 16;
constexpr int D    = 64;
constexpr int B    = 32768;
constexpr int COLS = 128;   // cols per tile (4 waves x 32)
constexpr int NT   = 4;     // tiles per block (pipelined)
constexpr int XS   = 133;   // x LDS row stride (frag reads 2 lanes/bank = free)
constexpr int CS   = 132;   // C LDS row stride (0 conflicts, r11-r14)

using bf16x8 = __attribute__((ext_vector_type(8))) short;
using f32x4  = __attribute__((ext_vector_type(4))) float;

__device__ inline unsigned pk2(float a, float b) {
    __hip_bfloat162 h2 = __float22bfloat162_rn(make_float2(a, b));
    union { __hip_bfloat162 h; unsigned u; } c;
    c.h = h2;
    return c.u;   // low 16 = a, high 16 = b
}

// Pre-kernel (validated r10-r14): Wt[(h*8 + ni*2 + ks)*64 + l] = bf16 frag
// chunk = W[h][16*ni + (l&15)][ks*32 + (l>>4)*8 + 0..7] packed as 4 u32.
__global__ void build_wt(const float* __restrict__ W, uint4* __restrict__ Wt)
{
    const int h = blockIdx.x;
    const int t = threadIdx.x;
    #pragma unroll
    for (int s = 0; s < 2; ++s) {
        const int c  = t + s * 256;
        const int g  = c >> 6;
        const int l  = c & 63;
        const int ni = g >> 1;
        const int ks = g & 1;
        const int row = 16 * ni + (l & 15);
        const int col = ks * 32 + (l >> 4) * 8;
        const float* src = W + ((size_t)h * D + row) * D + col;
        uint4 v;
        v.x = pk2(src[0], src[1]);
        v.y = pk2(src[2], src[3]);
        v.z = pk2(src[4], src[5]);
        v.w = pk2(src[6], src[7]);
        Wt[((size_t)h * 8 + g) * 64 + l] = v;
    }
}

__global__ __launch_bounds__(256)
void block_linear_mfma(const uint4* __restrict__ Wt,
                       const float* __restrict__ inp,
                       float* __restrict__ out)
{
    __shared__ float lds[D * XS];   // 34 KB; reused x -> C each tile

    const int tid = threadIdx.x;
    const int l   = tid & 63;
    const int wv  = __builtin_amdgcn_readfirstlane(tid >> 6);
    const int h   = blockIdx.y;
    const int l15 = l & 15;
    const int lk8 = (l >> 4) * 8;
    const int lr4 = (l >> 4) * 4;

    const unsigned colbase = (unsigned)blockIdx.x * (COLS * NT);

    const float* __restrict__ Xb = inp + (size_t)h * D * B;
    float*       __restrict__ Ob = out + (size_t)h * D * B;

    // Per-thread copy-pattern coords (1 KB contiguous per wave instr).
    const int prow = tid >> 5;          // rows 0..7 base (8 phases of 8 rows)
    const int pc4  = (tid & 31) << 2;   // 4-col group within 128

    // ---- W fragments: 8 coalesced uint4 from the hot table.
    bf16x8 bfrag[4][2];
    const uint4* wt = Wt + (size_t)h * 8 * 64 + l;
    #pragma unroll
    for (int ni = 0; ni < 4; ++ni)
        #pragma unroll
        for (int ks = 0; ks < 2; ++ks) {
            union { uint4 q; bf16x8 v; } u;
            u.q = wt[(ni * 2 + ks) * 64];
            bfrag[ni][ks] = u.v;
        }

    // ---- Prologue: issue tile-0 reads.
    float4 xcur[8], xnext[8];
    #pragma unroll
    for (int p = 0; p < 8; ++p)
        xcur[p] = *(const float4*)(Xb + (size_t)(p * 8 + prow) * B + colbase + pc4);

    #pragma unroll
    for (int t = 0; t < NT; ++t) {
        const unsigned tcol = colbase + t * COLS;

        // Phase 1: x -> LDS.
        #pragma unroll
        for (int p = 0; p < 8; ++p) {
            const int row = p * 8 + prow;
            lds[row * XS + pc4 + 0] = xcur[p].x;
            lds[row * XS + pc4 + 1] = xcur[p].y;
            lds[row * XS + pc4 + 2] = xcur[p].z;
            lds[row * XS + pc4 + 3] = xcur[p].w;
        }

        // Issue tile t+1 reads NOW — they fly through all later phases.
        if (t + 1 < NT) {
            #pragma unroll
            for (int p = 0; p < 8; ++p)
                xnext[p] = *(const float4*)(Xb + (size_t)(p * 8 + prow) * B
                                            + tcol + COLS + pc4);
        }

        __syncthreads();

        // Phase 2: A fragments from LDS.
        bf16x8 a[2][2];
        #pragma unroll
        for (int mi = 0; mi < 2; ++mi)
            #pragma unroll
            for (int ks = 0; ks < 2; ++ks) {
                const int c = wv * 32 + 16 * mi + l15;
                float e[8];
                #pragma unroll
                for (int r = 0; r < 8; ++r)
                    e[r] = lds[(ks * 32 + lk8 + r) * XS + c];
                union { bf16x8 v; unsigned u[4]; } f;
                f.u[0] = pk2(e[0], e[1]);
                f.u[1] = pk2(e[2], e[3]);
                f.u[2] = pk2(e[4], e[5]);
                f.u[3] = pk2(e[6], e[7]);
                a[mi][ks] = f.v;
            }
        __syncthreads();   // x reads done before C overwrites buffer

        // Phase 3: MFMA; C -> LDS.
        #pragma unroll
        for (int mi = 0; mi < 2; ++mi)
            #pragma unroll
            for (int ni = 0; ni < 4; ++ni) {
                f32x4 c = {0.f, 0.f, 0.f, 0.f};
                c = __builtin_amdgcn_mfma_f32_16x16x32_bf16(a[mi][0], bfrag[ni][0], c, 0, 0, 0);
                c = __builtin_amdgcn_mfma_f32_16x16x32_bf16(a[mi][1], bfrag[ni][1], c, 0, 0, 0);
                const int row  = 16 * ni + l15;
                const int colt = wv * 32 + 16 * mi + lr4;
                *(f32x4*)&lds[row * CS + colt] = c;
            }
        __syncthreads();

        // Phase 4: cooperative nt-stores (512 B runs).
        #pragma unroll
        for (int p = 0; p < 8; ++p) {
            const int row = p * 8 + prow;
            f32x4 v = *(const f32x4*)&lds[row * CS + pc4];
            __builtin_nontemporal_store(
                v, (f32x4*)(Ob + (size_t)row * B + tcol + pc4));
        }

        if (t + 1 < NT) {
            __syncthreads();   // store LDS-reads done before next x write
            #pragma unroll
            for (int p = 0; p < 8; ++p)
                xcur[p] = xnext[p];
        }
    }
}

extern "C" void kernel_launch(void* const* d_in, const int* in_sizes, int n_in,
                              void* d_out, int out_size, void* d_ws, size_t ws_size,
                              hipStream_t stream) {
    const float* W   = (const float*)d_in[0];
    const float* inp = (const float*)d_in[1];
    float*       out = (float*)d_out;
    uint4*       Wt  = (uint4*)d_ws;   // 128 KB fragment table

    build_wt<<<dim3(H), dim3(256), 0, stream>>>(W, Wt);

    dim3 grid(B / (COLS * NT), H);   // 64 x 16 = 1024 blocks (4/CU, 1 generation)
    block_linear_mfma<<<grid, dim3(256), 0, stream>>>(Wt, inp, out);
}

// Round 16
// 52.089 us; speedup vs baseline: 1.0321x; 1.0321x over previous
//
#include <hip/hip_runtime.h>
#include <hip/hip_bf16.h>

// BlockLinear: out[h*64+i][b] = sum_j W[h][i][j] * inp[h*64+j][b]
// Round 16: r14 EXACTLY (best: 49.5 us), minus the build_wt pre-kernel.
// W fragments are built in-block from raw W (r8's ordering: W loads issued
// FIRST, then x loads, then W-convert -> counted vmcnt leaves x in flight).
// r15's cross-tile pipeline reverted (regressed 49.5->53.8: extra barrier +
// fewer blocks beat the prefetch gain).
// Kept wins: copy-style 1 KB read instrs (r14), LDS-staged C + cooperative
// f32x4 nt-stores on 512 B runs (r11/r13), single 34 KB LDS buffer.
// Fragment layout (HW-validated r6-r15): lane l holds k = ks*32+8*(l>>4)+r;
// C/D: batch col m = 4*(l>>4)+reg, output row n = l&15.

constexpr int H    = 16;
constexpr int D    = 64;
constexpr int B    = 32768;
constexpr int COLS = 128;   // cols per block (4 waves x 32)
constexpr int XS   = 133;   // x LDS row stride (frag reads 2 lanes/bank = free)
constexpr int CS   = 132;   // C LDS row stride

using bf16x8 = __attribute__((ext_vector_type(8))) short;
using f32x4  = __attribute__((ext_vector_type(4))) float;

__device__ inline unsigned pk2(float a, float b) {
    __hip_bfloat162 h2 = __float22bfloat162_rn(make_float2(a, b));
    union { __hip_bfloat162 h; unsigned u; } c;
    c.h = h2;
    return c.u;   // low 16 = a, high 16 = b
}

__global__ __launch_bounds__(256)
void block_linear_mfma(const float* __restrict__ W,
                       const float* __restrict__ inp,
                       float* __restrict__ out)
{
    __shared__ float lds[D * XS];   // 34 KB; reused x -> C

    const int tid = threadIdx.x;
    const int l   = tid & 63;
    const int wv  = __builtin_amdgcn_readfirstlane(tid >> 6);
    const int h   = blockIdx.y;
    const int l15 = l & 15;
    const int lk8 = (l >> 4) * 8;
    const int lr4 = (l >> 4) * 4;

    const unsigned colbase = (unsigned)blockIdx.x * COLS;

    const float* __restrict__ Xb = inp + (size_t)h * D * B;
    float*       __restrict__ Ob = out + (size_t)h * D * B;

    // Copy-pattern coords (1 KB contiguous per wave instr).
    const int prow = tid >> 5;          // row base within 8-row group
    const int pc4  = (tid & 31) << 2;   // 4-col group within 128

    // ---- 1) Issue W raw loads FIRST (L2/L3-hot after first generation).
    float4 wq[4][2][2];
    #pragma unroll
    for (int ni = 0; ni < 4; ++ni) {
        const float* wp = W + ((size_t)h * D + 16 * ni + l15) * D + lk8;
        #pragma unroll
        for (int ks = 0; ks < 2; ++ks) {
            wq[ni][ks][0] = *(const float4*)(wp + ks * 32);
            wq[ni][ks][1] = *(const float4*)(wp + ks * 32 + 4);
        }
    }

    // ---- 2) Issue copy-style x reads (8 x 1 KB wave instrs) while W flies.
    float4 xp[8];
    #pragma unroll
    for (int p = 0; p < 8; ++p)
        xp[p] = *(const float4*)(Xb + (size_t)(p * 8 + prow) * B + colbase + pc4);

    // ---- 3) Convert W -> B fragments (waits only W's loads; x stays in flight).
    bf16x8 bfrag[4][2];
    #pragma unroll
    for (int ni = 0; ni < 4; ++ni)
        #pragma unroll
        for (int ks = 0; ks < 2; ++ks) {
            union { bf16x8 v; unsigned u[4]; } f;
            f.u[0] = pk2(wq[ni][ks][0].x, wq[ni][ks][0].y);
            f.u[1] = pk2(wq[ni][ks][0].z, wq[ni][ks][0].w);
            f.u[2] = pk2(wq[ni][ks][1].x, wq[ni][ks][1].y);
            f.u[3] = pk2(wq[ni][ks][1].z, wq[ni][ks][1].w);
            bfrag[ni][ks] = f.v;
        }

    // ---- 4) x -> LDS (row-major, stride 133).
    #pragma unroll
    for (int p = 0; p < 8; ++p) {
        const int row = p * 8 + prow;
        lds[row * XS + pc4 + 0] = xp[p].x;
        lds[row * XS + pc4 + 1] = xp[p].y;
        lds[row * XS + pc4 + 2] = xp[p].z;
        lds[row * XS + pc4 + 3] = xp[p].w;
    }
    __syncthreads();

    // ---- 5) A fragments from LDS (2 lanes/bank = free at stride 133).
    bf16x8 a[2][2];
    #pragma unroll
    for (int mi = 0; mi < 2; ++mi)
        #pragma unroll
        for (int ks = 0; ks < 2; ++ks) {
            const int c = wv * 32 + 16 * mi + l15;
            float e[8];
            #pragma unroll
            for (int r = 0; r < 8; ++r)
                e[r] = lds[(ks * 32 + lk8 + r) * XS + c];
            union { bf16x8 v; unsigned u[4]; } f;
            f.u[0] = pk2(e[0], e[1]);
            f.u[1] = pk2(e[2], e[3]);
            f.u[2] = pk2(e[4], e[5]);
            f.u[3] = pk2(e[6], e[7]);
            a[mi][ks] = f.v;
        }
    __syncthreads();   // all x reads done before C overwrites the buffer

    // ---- 6) MFMA; stage C into the same LDS (stride 132).
    #pragma unroll
    for (int mi = 0; mi < 2; ++mi)
        #pragma unroll
        for (int ni = 0; ni < 4; ++ni) {
            f32x4 c = {0.f, 0.f, 0.f, 0.f};
            c = __builtin_amdgcn_mfma_f32_16x16x32_bf16(a[mi][0], bfrag[ni][0], c, 0, 0, 0);
            c = __builtin_amdgcn_mfma_f32_16x16x32_bf16(a[mi][1], bfrag[ni][1], c, 0, 0, 0);
            const int row  = 16 * ni + l15;
            const int colt = wv * 32 + 16 * mi + lr4;
            *(f32x4*)&lds[row * CS + colt] = c;
        }
    __syncthreads();

    // ---- 7) Cooperative nt-stores, f32x4 (two 512 B runs per wave instr).
    #pragma unroll
    for (int p = 0; p < 8; ++p) {
        const int row = p * 8 + prow;
        f32x4 v = *(const f32x4*)&lds[row * CS + pc4];
        __builtin_nontemporal_store(
            v, (f32x4*)(Ob + (size_t)row * B + colbase + pc4));
    }
}

extern "C" void kernel_launch(void* const* d_in, const int* in_sizes, int n_in,
                              void* d_out, int out_size, void* d_ws, size_t ws_size,
                              hipStream_t stream) {
    const float* W   = (const float*)d_in[0];
    const float* inp = (const float*)d_in[1];
    float*       out = (float*)d_out;

    dim3 grid(B / COLS, H);   // 256 x 16 = 4096 workgroups, single kernel
    block_linear_mfma<<<grid, dim3(256), 0, stream>>>(W, inp, out);
}

// Round 17
// 49.483 us; speedup vs baseline: 1.0864x; 1.0527x over previous
//
#include <hip/hip_runtime.h>
#include <hip/hip_bf16.h>

// BlockLinear: out[h*64+i][b] = sum_j W[h][i][j] * inp[h*64+j][b]
// Round 17: r14 (best, 49.5 us) with phase-1 replaced by global_load_lds DMA:
//  - 8 x global_load_lds_dwordx4 per wave stage 8 KB straight to LDS
//    (no VGPR roundtrip, linear writes = 0 write-side bank conflicts).
//  - LDS x-rows are linear 128 floats; the 4-way read conflict that linear
//    rows would cause is killed by PRE-SWIZZLING the global source chunk:
//    src16B ^= ((row>>3)&3)<<5. Phase-2 read index: row*128 + (c ^ lk8)
//    (the row XOR term == lane's lk8; element-traced for correctness).
//  - Everything else r14-exact: build_wt fragment table (r16 showed removing
//    it costs 2.6 us), C staged at stride 132, cooperative f32x4 nt-stores.
// Fragment layout (HW-validated r6-r16): lane l holds k = ks*32+8*(l>>4)+r;
// C/D: batch col m = 4*(l>>4)+reg, output row n = l&15.

constexpr int H    = 16;
constexpr int D    = 64;
constexpr int B    = 32768;
constexpr int COLS = 128;   // cols per block (4 waves x 32)
constexpr int CS   = 132;   // C LDS row stride (floats); x uses linear 128

using bf16x8 = __attribute__((ext_vector_type(8))) short;
using f32x4  = __attribute__((ext_vector_type(4))) float;

__device__ inline unsigned pk2(float a, float b) {
    __hip_bfloat162 h2 = __float22bfloat162_rn(make_float2(a, b));
    union { __hip_bfloat162 h; unsigned u; } c;
    c.h = h2;
    return c.u;   // low 16 = a, high 16 = b
}

// Pre-kernel (validated r10-r16): Wt[(h*8 + ni*2 + ks)*64 + l] = bf16 frag
// chunk = W[h][16*ni + (l&15)][ks*32 + (l>>4)*8 + 0..7] packed as 4 u32.
__global__ void build_wt(const float* __restrict__ W, uint4* __restrict__ Wt)
{
    const int h = blockIdx.x;
    const int t = threadIdx.x;
    #pragma unroll
    for (int s = 0; s < 2; ++s) {
        const int c  = t + s * 256;
        const int g  = c >> 6;
        const int l  = c & 63;
        const int ni = g >> 1;
        const int ks = g & 1;
        const int row = 16 * ni + (l & 15);
        const int col = ks * 32 + (l >> 4) * 8;
        const float* src = W + ((size_t)h * D + row) * D + col;
        uint4 v;
        v.x = pk2(src[0], src[1]);
        v.y = pk2(src[2], src[3]);
        v.z = pk2(src[4], src[5]);
        v.w = pk2(src[6], src[7]);
        Wt[((size_t)h * 8 + g) * 64 + l] = v;
    }
}

__global__ __launch_bounds__(256)
void block_linear_mfma(const uint4* __restrict__ Wt,
                       const float* __restrict__ inp,
                       float* __restrict__ out)
{
    __shared__ float lds[D * CS];   // 33.8 KB; x uses [0, 64*128), C uses stride 132

    const int tid = threadIdx.x;
    const int l   = tid & 63;
    const int wv  = __builtin_amdgcn_readfirstlane(tid >> 6);
    const int h   = blockIdx.y;
    const int l15 = l & 15;
    const int lk8 = (l >> 4) * 8;
    const int lr4 = (l >> 4) * 4;

    const unsigned colbase = (unsigned)blockIdx.x * COLS;

    const float* __restrict__ Xb = inp + (size_t)h * D * B;
    float*       __restrict__ Ob = out + (size_t)h * D * B;

    // Copy-pattern coords for the store phase.
    const int prow = tid >> 5;          // row base within 8-row group
    const int pc4  = (tid & 31) << 2;   // 4-col group within 128

    // ---- 1) W fragments: 8 coalesced uint4 from the hot table.
    bf16x8 bfrag[4][2];
    const uint4* wt = Wt + (size_t)h * 8 * 64 + l;
    #pragma unroll
    for (int ni = 0; ni < 4; ++ni)
        #pragma unroll
        for (int ks = 0; ks < 2; ++ks) {
            union { uint4 q; bf16x8 v; } u;
            u.q = wt[(ni * 2 + ks) * 64];
            bfrag[ni][ks] = u.v;
        }

    // ---- 2) Stage x via global_load_lds DMA (8 x 1 KB per wave).
    // Chunk q = wv*8+p covers rows 2q, 2q+1 (512 B each), LDS linear.
    // Source 16 B-chunk pre-swizzled: ^ ((row>>3)&3)<<5.
    const int i31 = l & 31;
    const int rh  = l >> 5;
    #pragma unroll
    for (int p = 0; p < 8; ++p) {
        const int q   = wv * 8 + p;
        const int row = 2 * q + rh;
        const unsigned swz = (unsigned)((row >> 3) & 3) << 5;   // bytes
        const char* g = (const char*)(Xb + (size_t)row * B + colbase)
                        + (((unsigned)i31 * 16) ^ swz);
        __builtin_amdgcn_global_load_lds(
            (const __attribute__((address_space(1))) void*)g,
            (__attribute__((address_space(3))) void*)&lds[q * 256],
            16, 0, 0);
    }
    __syncthreads();   // drains the DMA (vmcnt) + syncs block

    // ---- 3) A fragments from swizzled-linear LDS.
    // LDS[row*128 + f] = X[row][f ^ ((row>>3)&3)<<3]; for our rows the XOR
    // term equals lk8, so X[row][c] sits at row*128 + (c ^ lk8).
    bf16x8 a[2][2];
    #pragma unroll
    for (int mi = 0; mi < 2; ++mi)
        #pragma unroll
        for (int ks = 0; ks < 2; ++ks) {
            const int c = (wv * 32 + 16 * mi + l15) ^ lk8;
            float e[8];
            #pragma unroll
            for (int r = 0; r < 8; ++r)
                e[r] = lds[(ks * 32 + lk8 + r) * 128 + c];
            union { bf16x8 v; unsigned u[4]; } f;
            f.u[0] = pk2(e[0], e[1]);
            f.u[1] = pk2(e[2], e[3]);
            f.u[2] = pk2(e[4], e[5]);
            f.u[3] = pk2(e[6], e[7]);
            a[mi][ks] = f.v;
        }
    __syncthreads();   // all x reads done before C overwrites the buffer

    // ---- 4) MFMA; stage C into LDS (stride 132).
    #pragma unroll
    for (int mi = 0; mi < 2; ++mi)
        #pragma unroll
        for (int ni = 0; ni < 4; ++ni) {
            f32x4 c = {0.f, 0.f, 0.f, 0.f};
            c = __builtin_amdgcn_mfma_f32_16x16x32_bf16(a[mi][0], bfrag[ni][0], c, 0, 0, 0);
            c = __builtin_amdgcn_mfma_f32_16x16x32_bf16(a[mi][1], bfrag[ni][1], c, 0, 0, 0);
            const int row  = 16 * ni + l15;
            const int colt = wv * 32 + 16 * mi + lr4;
            *(f32x4*)&lds[row * CS + colt] = c;
        }
    __syncthreads();

    // ---- 5) Cooperative nt-stores, f32x4 (two 512 B runs per wave instr).
    #pragma unroll
    for (int p = 0; p < 8; ++p) {
        const int row = p * 8 + prow;
        f32x4 v = *(const f32x4*)&lds[row * CS + pc4];
        __builtin_nontemporal_store(
            v, (f32x4*)(Ob + (size_t)row * B + colbase + pc4));
    }
}

extern "C" void kernel_launch(void* const* d_in, const int* in_sizes, int n_in,
                              void* d_out, int out_size, void* d_ws, size_t ws_size,
                              hipStream_t stream) {
    const float* W   = (const float*)d_in[0];
    const float* inp = (const float*)d_in[1];
    float*       out = (float*)d_out;
    uint4*       Wt  = (uint4*)d_ws;   // 128 KB fragment table

    build_wt<<<dim3(H), dim3(256), 0, stream>>>(W, Wt);

    dim3 grid(B / COLS, H);   // 256 x 16 = 4096 workgroups
    block_linear_mfma<<<grid, dim3(256), 0, stream>>>(Wt, inp, out);
}